// Round 2
// baseline (1036.207 us; speedup 1.0000x reference)
//
#include <hip/hip_runtime.h>
#include <cstddef>

typedef __bf16 bf16x8 __attribute__((ext_vector_type(8)));
typedef float  f32x4  __attribute__((ext_vector_type(4)));

__device__ __forceinline__ float bf2f(unsigned short s) {
    return __uint_as_float(((unsigned int)s) << 16);
}
__device__ __forceinline__ unsigned short f2bf(float x) {
    unsigned int u = __float_as_uint(x);
    unsigned int r = u + 0x7fffu + ((u >> 16) & 1u);   // RNE
    return (unsigned short)(r >> 16);
}
__device__ __forceinline__ void unpack8(uint4 u, float* f) {
    f[0] = __uint_as_float(u.x << 16);
    f[1] = __uint_as_float(u.x & 0xffff0000u);
    f[2] = __uint_as_float(u.y << 16);
    f[3] = __uint_as_float(u.y & 0xffff0000u);
    f[4] = __uint_as_float(u.z << 16);
    f[5] = __uint_as_float(u.z & 0xffff0000u);
    f[6] = __uint_as_float(u.w << 16);
    f[7] = __uint_as_float(u.w & 0xffff0000u);
}

// ---------------------------------------------------------------------------
// dtype detector: bf16 N(0,1) data has exponent fields in ~[0x50,0x82];
// fp32 data read as ushorts has random exponents on even indices (~70% wild).
// ---------------------------------------------------------------------------
__global__ __launch_bounds__(256) void detect_dtype_kernel(
    const unsigned short* __restrict__ x, int* __restrict__ flag)
{
    __shared__ int cnt;
    if (threadIdx.x == 0) cnt = 0;
    __syncthreads();
    int wild = 0;
    for (int k = 0; k < 16; ++k) {
        unsigned short u = x[(size_t)((k * 256 + threadIdx.x) << 1)];
        int e = (u >> 7) & 0xFF;
        wild += ((e >= 0x90) || (e >= 1 && e <= 0x48)) ? 1 : 0;
    }
    atomicAdd(&cnt, wild);
    __syncthreads();
    if (threadIdx.x == 0) *flag = (cnt > 512) ? 1 : 0;
}

// ---------------------------------------------------------------------------
// GEMM mainloop: C_tile(64x64) = A[m0:m0+64,:] * B[:,n0:n0+64], BK=32.
// A row-major [M,K], B row-major [K,N]; dtype per template (fp32 converts to
// bf16 during staging). B staged TRANSPOSED (BsT[n][k]) so both fragment
// reads are contiguous ds_read_b128.
// ---------------------------------------------------------------------------
template<bool AFP32, bool BFP32>
__device__ __forceinline__ void gemm_mainloop(
    const void* __restrict__ Av, const void* __restrict__ Bv,
    int K, int N, int m0, int n0,
    unsigned short* As, unsigned short* BsT, f32x4* acc)
{
    const int tid  = threadIdx.x;
    const int wave = tid >> 6;
    const int lane = tid & 63;
    const int mrow = lane & 15;
    const int quad = lane >> 4;

    const int a_row = tid >> 2;
    const int a_col = (tid & 3) << 3;
    const int kb2 = (tid & 15) << 1;
    const int nb1 = (tid >> 4) << 1;     // 0..30 even
    const int nb2 = nb1 + 32;            // 32..62 even

    for (int k0 = 0; k0 < K; k0 += 32) {
        // ---- A tile 64x32 ----
        uint4 av;
        if (AFP32) {
            const float* Af = (const float*)Av;
            const float* ap = Af + (size_t)(m0 + a_row) * K + k0 + a_col;
            float4 a0 = *(const float4*)ap;
            float4 a1 = *(const float4*)(ap + 4);
            av.x = (unsigned)f2bf(a0.x) | ((unsigned)f2bf(a0.y) << 16);
            av.y = (unsigned)f2bf(a0.z) | ((unsigned)f2bf(a0.w) << 16);
            av.z = (unsigned)f2bf(a1.x) | ((unsigned)f2bf(a1.y) << 16);
            av.w = (unsigned)f2bf(a1.z) | ((unsigned)f2bf(a1.w) << 16);
        } else {
            const unsigned short* Ab = (const unsigned short*)Av;
            av = *(const uint4*)(Ab + (size_t)(m0 + a_row) * K + k0 + a_col);
        }
        // ---- B 2x2 blocks, transposed into BsT[n][k] ----
        unsigned int t0, t1, t2, t3;   // BsT words for rows nb1, nb1+1, nb2, nb2+1
        if (BFP32) {
            const float* Bf = (const float*)Bv;
            const float* bp = Bf + (size_t)(k0 + kb2) * N + n0;
            float2 r0 = *(const float2*)(bp + nb1);
            float2 r1 = *(const float2*)(bp + N + nb1);
            float2 r2 = *(const float2*)(bp + nb2);
            float2 r3 = *(const float2*)(bp + N + nb2);
            t0 = (unsigned)f2bf(r0.x) | ((unsigned)f2bf(r1.x) << 16);
            t1 = (unsigned)f2bf(r0.y) | ((unsigned)f2bf(r1.y) << 16);
            t2 = (unsigned)f2bf(r2.x) | ((unsigned)f2bf(r3.x) << 16);
            t3 = (unsigned)f2bf(r2.y) | ((unsigned)f2bf(r3.y) << 16);
        } else {
            const unsigned short* Bb = (const unsigned short*)Bv;
            const unsigned short* bp = Bb + (size_t)(k0 + kb2) * N + n0;
            unsigned int r0 = *(const unsigned int*)(bp + nb1);
            unsigned int r1 = *(const unsigned int*)(bp + N + nb1);
            unsigned int r2 = *(const unsigned int*)(bp + nb2);
            unsigned int r3 = *(const unsigned int*)(bp + N + nb2);
            t0 = (r0 & 0xffffu) | (r1 << 16);
            t1 = (r0 >> 16) | (r1 & 0xffff0000u);
            t2 = (r2 & 0xffffu) | (r3 << 16);
            t3 = (r2 >> 16) | (r3 & 0xffff0000u);
        }

        *(uint4*)(As + a_row * 32 + a_col) = av;
        *(unsigned int*)(BsT + nb1 * 32 + kb2)       = t0;
        *(unsigned int*)(BsT + (nb1 + 1) * 32 + kb2) = t1;
        *(unsigned int*)(BsT + nb2 * 32 + kb2)       = t2;
        *(unsigned int*)(BsT + (nb2 + 1) * 32 + kb2) = t3;
        __syncthreads();

        bf16x8 af = *(const bf16x8*)(As + (wave * 16 + mrow) * 32 + quad * 8);
        #pragma unroll
        for (int nt = 0; nt < 4; ++nt) {
            bf16x8 bfv = *(const bf16x8*)(BsT + (nt * 16 + mrow) * 32 + quad * 8);
            acc[nt] = __builtin_amdgcn_mfma_f32_16x16x32_bf16(af, bfv, acc[nt], 0, 0, 0);
        }
        __syncthreads();
    }
}

// ---------------------------------------------------------------------------
// QKV GEMM body
// ---------------------------------------------------------------------------
template<bool FP32>
__device__ __forceinline__ void qkv_body(
    const void* A, const void* Bw, const void* bias,
    unsigned short* Qb, unsigned short* Kb, unsigned short* Vb,
    unsigned short* As, unsigned short* BsT)
{
    const int K = 1024, N = 3072;
    const int m0 = blockIdx.y * 64;
    const int n0 = blockIdx.x * 64;

    f32x4 acc[4];
    #pragma unroll
    for (int nt = 0; nt < 4; ++nt) { acc[nt][0]=0.f; acc[nt][1]=0.f; acc[nt][2]=0.f; acc[nt][3]=0.f; }

    gemm_mainloop<FP32, FP32>(A, Bw, K, N, m0, n0, As, BsT, acc);

    const int tid  = threadIdx.x;
    const int wave = tid >> 6;
    const int lane = tid & 63;
    const int mrow = lane & 15;
    const int quad = lane >> 4;

    const int sel = n0 >> 10;
    const int h   = (n0 & 1023) >> 6;
    unsigned short* dst = (sel == 0) ? Qb : (sel == 1) ? Kb : Vb;

    #pragma unroll
    for (int nt = 0; nt < 4; ++nt) {
        const int d  = nt * 16 + mrow;
        const float bv = FP32 ? ((const float*)bias)[n0 + d]
                              : bf2f(((const unsigned short*)bias)[n0 + d]);
        #pragma unroll
        for (int r = 0; r < 4; ++r) {
            const int m  = m0 + wave * 16 + quad * 4 + r;
            const int bb = m >> 11;
            const int t  = m & 2047;
            dst[(((size_t)(bb * 16 + h) * 2048 + t) << 6) + d] = f2bf(acc[nt][r] + bv);
        }
    }
}

__global__ __launch_bounds__(256) void gemm_qkv_kernel(
    const int* __restrict__ flag,
    const void* __restrict__ A, const void* __restrict__ Bw,
    const void* __restrict__ bias,
    unsigned short* __restrict__ Qb, unsigned short* __restrict__ Kb,
    unsigned short* __restrict__ Vb)
{
    __shared__ unsigned short As[64 * 32];
    __shared__ unsigned short BsT[64 * 32];
    if (*flag) qkv_body<true >(A, Bw, bias, Qb, Kb, Vb, As, BsT);
    else       qkv_body<false>(A, Bw, bias, Qb, Kb, Vb, As, BsT);
}

// ---------------------------------------------------------------------------
// Proj GEMM body: A = Attn (always bf16 internal), B/bias/out per flag
// ---------------------------------------------------------------------------
template<bool FP32>
__device__ __forceinline__ void proj_body(
    const unsigned short* A, const void* Bw, const void* bias, void* Out,
    unsigned short* As, unsigned short* BsT)
{
    const int K = 1024, N = 1024;
    const int m0 = blockIdx.y * 64;
    const int n0 = blockIdx.x * 64;

    f32x4 acc[4];
    #pragma unroll
    for (int nt = 0; nt < 4; ++nt) { acc[nt][0]=0.f; acc[nt][1]=0.f; acc[nt][2]=0.f; acc[nt][3]=0.f; }

    gemm_mainloop<false, FP32>(A, Bw, K, N, m0, n0, As, BsT, acc);

    const int tid  = threadIdx.x;
    const int wave = tid >> 6;
    const int lane = tid & 63;
    const int mrow = lane & 15;
    const int quad = lane >> 4;

    #pragma unroll
    for (int nt = 0; nt < 4; ++nt) {
        const int n  = n0 + nt * 16 + mrow;
        const float bv = FP32 ? ((const float*)bias)[n]
                              : bf2f(((const unsigned short*)bias)[n]);
        #pragma unroll
        for (int r = 0; r < 4; ++r) {
            const int m = m0 + wave * 16 + quad * 4 + r;
            const float val = acc[nt][r] + bv;
            if (FP32) ((float*)Out)[(size_t)m * 1024 + n] = val;
            else      ((unsigned short*)Out)[(size_t)m * 1024 + n] = f2bf(val);
        }
    }
}

__global__ __launch_bounds__(256) void gemm_proj_kernel(
    const int* __restrict__ flag,
    const unsigned short* __restrict__ A, const void* __restrict__ Bw,
    const void* __restrict__ bias, void* __restrict__ Out)
{
    __shared__ unsigned short As[64 * 32];
    __shared__ unsigned short BsT[64 * 32];
    if (*flag) proj_body<true >(A, Bw, bias, Out, As, BsT);
    else       proj_body<false>(A, Bw, bias, Out, As, BsT);
}

// ---------------------------------------------------------------------------
// Flash-style causal attention, fp32 vector math, bf16 internal tensors.
// ---------------------------------------------------------------------------
__global__ __launch_bounds__(256) void attn_kernel(
    const unsigned short* __restrict__ Qb,
    const unsigned short* __restrict__ Kb,
    const unsigned short* __restrict__ Vb,
    unsigned short* __restrict__ Attn)
{
    __shared__ float KsT[64][64];   // [d][j]
    __shared__ float Vs[64][64];    // [j][d]

    const int tid   = threadIdx.x;
    const int bh    = blockIdx.y;           // 0..31
    const int q0    = blockIdx.x << 5;      // 32-query block
    const int q     = tid >> 3;             // 0..31
    const int slice = tid & 7;
    const int j0    = slice << 3;
    const int ds    = slice << 3;
    const int qg    = q0 + q;
    const int lane  = tid & 63;
    const int sr = tid >> 2;
    const int sc = (tid & 3) << 4;

    float qreg[64];
    {
        const uint4* qp = (const uint4*)(Qb + ((size_t)bh * 2048 + qg) * 64);
        #pragma unroll
        for (int c = 0; c < 8; ++c) {
            uint4 u = qp[c];
            float f[8]; unpack8(u, f);
            #pragma unroll
            for (int e = 0; e < 8; ++e) qreg[c * 8 + e] = f[e] * 0.125f;
        }
    }

    float O[8] = {0.f,0.f,0.f,0.f,0.f,0.f,0.f,0.f};
    float m_run = -1e30f, l_run = 0.f;

    const int ntiles = ((q0 + 31) >> 6) + 1;
    for (int tile = 0; tile < ntiles; ++tile) {
        const int kt0 = tile << 6;
        {
            const size_t rb = ((size_t)bh * 2048 + kt0 + sr) * 64 + sc;
            uint4 u0 = *(const uint4*)(Kb + rb);
            uint4 u1 = *(const uint4*)(Kb + rb + 8);
            float f[16]; unpack8(u0, f); unpack8(u1, f + 8);
            #pragma unroll
            for (int c = 0; c < 16; ++c) KsT[sc + c][sr] = f[c];
            uint4 w0 = *(const uint4*)(Vb + rb);
            uint4 w1 = *(const uint4*)(Vb + rb + 8);
            float g[16]; unpack8(w0, g); unpack8(w1, g + 8);
            *(float4*)&Vs[sr][sc + 0]  = make_float4(g[0],  g[1],  g[2],  g[3]);
            *(float4*)&Vs[sr][sc + 4]  = make_float4(g[4],  g[5],  g[6],  g[7]);
            *(float4*)&Vs[sr][sc + 8]  = make_float4(g[8],  g[9],  g[10], g[11]);
            *(float4*)&Vs[sr][sc + 12] = make_float4(g[12], g[13], g[14], g[15]);
        }
        __syncthreads();

        float s[8] = {0.f,0.f,0.f,0.f,0.f,0.f,0.f,0.f};
        #pragma unroll
        for (int d = 0; d < 64; ++d) {
            const float qd = qreg[d];
            const float4 k0 = *(const float4*)&KsT[d][j0];
            const float4 k1 = *(const float4*)&KsT[d][j0 + 4];
            s[0] = fmaf(qd, k0.x, s[0]); s[1] = fmaf(qd, k0.y, s[1]);
            s[2] = fmaf(qd, k0.z, s[2]); s[3] = fmaf(qd, k0.w, s[3]);
            s[4] = fmaf(qd, k1.x, s[4]); s[5] = fmaf(qd, k1.y, s[5]);
            s[6] = fmaf(qd, k1.z, s[6]); s[7] = fmaf(qd, k1.w, s[7]);
        }
        bool msk[8];
        #pragma unroll
        for (int i = 0; i < 8; ++i) {
            msk[i] = (kt0 + j0 + i > qg);
            if (msk[i]) s[i] = -1e30f;
        }

        float mx = fmaxf(fmaxf(fmaxf(s[0], s[1]), fmaxf(s[2], s[3])),
                         fmaxf(fmaxf(s[4], s[5]), fmaxf(s[6], s[7])));
        mx = fmaxf(mx, __shfl_xor(mx, 1));
        mx = fmaxf(mx, __shfl_xor(mx, 2));
        mx = fmaxf(mx, __shfl_xor(mx, 4));
        const float m_new = fmaxf(m_run, mx);
        const float alpha = __expf(m_run - m_new);
        float p[8], ps = 0.f;
        #pragma unroll
        for (int i = 0; i < 8; ++i) {
            p[i] = msk[i] ? 0.f : __expf(s[i] - m_new);
            ps += p[i];
        }
        ps += __shfl_xor(ps, 1);
        ps += __shfl_xor(ps, 2);
        ps += __shfl_xor(ps, 4);
        l_run = l_run * alpha + ps;
        m_run = m_new;
        #pragma unroll
        for (int c = 0; c < 8; ++c) O[c] *= alpha;

        #pragma unroll
        for (int src = 0; src < 8; ++src) {
            #pragma unroll
            for (int i = 0; i < 8; ++i) {
                const float pj = __shfl(p[i], (lane & 56) | src);
                const int  j   = src * 8 + i;
                const float4 v0 = *(const float4*)&Vs[j][ds];
                const float4 v1 = *(const float4*)&Vs[j][ds + 4];
                O[0] = fmaf(pj, v0.x, O[0]); O[1] = fmaf(pj, v0.y, O[1]);
                O[2] = fmaf(pj, v0.z, O[2]); O[3] = fmaf(pj, v0.w, O[3]);
                O[4] = fmaf(pj, v1.x, O[4]); O[5] = fmaf(pj, v1.y, O[5]);
                O[6] = fmaf(pj, v1.z, O[6]); O[7] = fmaf(pj, v1.w, O[7]);
            }
        }
        __syncthreads();
    }

    const float inv_l = 1.0f / l_run;
    unsigned short o16[8];
    #pragma unroll
    for (int c = 0; c < 8; ++c) o16[c] = f2bf(O[c] * inv_l);
    const int b = bh >> 4, h = bh & 15;
    *(uint4*)(Attn + ((size_t)(b * 2048 + qg)) * 1024 + h * 64 + ds) = *(uint4*)o16;
}

// ---------------------------------------------------------------------------
extern "C" void kernel_launch(void* const* d_in, const int* in_sizes, int n_in,
                              void* d_out, int out_size, void* d_ws, size_t ws_size,
                              hipStream_t stream)
{
    const void* x     = d_in[0];
    const void* Wqkv  = d_in[1];
    const void* bqkv  = d_in[2];
    const void* Wproj = d_in[3];
    const void* bproj = d_in[4];

    int* flag = (int*)d_ws;
    unsigned short* ws   = (unsigned short*)d_ws;
    unsigned short* Qb   = ws + 64;                // [B,H,T,D] = 4194304 each
    unsigned short* Kb   = Qb + 4194304;
    unsigned short* Vb   = Kb + 4194304;
    unsigned short* Attn = Vb + 4194304;           // [B*T, 1024]

    detect_dtype_kernel<<<1, 256, 0, stream>>>((const unsigned short*)x, flag);
    gemm_qkv_kernel<<<dim3(48, 64), 256, 0, stream>>>(flag, x, Wqkv, bqkv, Qb, Kb, Vb);
    attn_kernel<<<dim3(64, 32), 256, 0, stream>>>(Qb, Kb, Vb, Attn);
    gemm_proj_kernel<<<dim3(16, 64), 256, 0, stream>>>(flag, Attn, Wproj, bproj, d_out);
}

// Round 4
// 430.911 us; speedup vs baseline: 2.4047x; 2.4047x over previous
//
#include <hip/hip_runtime.h>
#include <cstddef>

typedef __bf16 bf16x8 __attribute__((ext_vector_type(8)));
typedef float  f32x4  __attribute__((ext_vector_type(4)));

__device__ __forceinline__ float bf2f(unsigned short s) {
    return __uint_as_float(((unsigned int)s) << 16);
}
__device__ __forceinline__ unsigned short f2bf(float x) {
    unsigned int u = __float_as_uint(x);
    unsigned int r = u + 0x7fffu + ((u >> 16) & 1u);   // RNE
    return (unsigned short)(r >> 16);
}

// ---------------------------------------------------------------------------
// dtype detector (inputs confirmed fp32; cheap insurance, input-agnostic)
// ---------------------------------------------------------------------------
__global__ __launch_bounds__(256) void detect_dtype_kernel(
    const unsigned short* __restrict__ x, int* __restrict__ flag)
{
    __shared__ int cnt;
    if (threadIdx.x == 0) cnt = 0;
    __syncthreads();
    int wild = 0;
    for (int k = 0; k < 16; ++k) {
        unsigned short u = x[(size_t)((k * 256 + threadIdx.x) << 1)];
        int e = (u >> 7) & 0xFF;
        wild += ((e >= 0x90) || (e >= 1 && e <= 0x48)) ? 1 : 0;
    }
    atomicAdd(&cnt, wild);
    __syncthreads();
    if (threadIdx.x == 0) *flag = (cnt > 512) ? 1 : 0;
}

// ---------------------------------------------------------------------------
// GEMM mainloop (known-correct from R2)
// ---------------------------------------------------------------------------
template<bool AFP32, bool BFP32>
__device__ __forceinline__ void gemm_mainloop(
    const void* __restrict__ Av, const void* __restrict__ Bv,
    int K, int N, int m0, int n0,
    unsigned short* As, unsigned short* BsT, f32x4* acc)
{
    const int tid  = threadIdx.x;
    const int wave = tid >> 6;
    const int lane = tid & 63;
    const int mrow = lane & 15;
    const int quad = lane >> 4;

    const int a_row = tid >> 2;
    const int a_col = (tid & 3) << 3;
    const int kb2 = (tid & 15) << 1;
    const int nb1 = (tid >> 4) << 1;
    const int nb2 = nb1 + 32;

    for (int k0 = 0; k0 < K; k0 += 32) {
        uint4 av;
        if (AFP32) {
            const float* Af = (const float*)Av;
            const float* ap = Af + (size_t)(m0 + a_row) * K + k0 + a_col;
            float4 a0 = *(const float4*)ap;
            float4 a1 = *(const float4*)(ap + 4);
            av.x = (unsigned)f2bf(a0.x) | ((unsigned)f2bf(a0.y) << 16);
            av.y = (unsigned)f2bf(a0.z) | ((unsigned)f2bf(a0.w) << 16);
            av.z = (unsigned)f2bf(a1.x) | ((unsigned)f2bf(a1.y) << 16);
            av.w = (unsigned)f2bf(a1.z) | ((unsigned)f2bf(a1.w) << 16);
        } else {
            const unsigned short* Ab = (const unsigned short*)Av;
            av = *(const uint4*)(Ab + (size_t)(m0 + a_row) * K + k0 + a_col);
        }
        unsigned int t0, t1, t2, t3;
        if (BFP32) {
            const float* Bf = (const float*)Bv;
            const float* bp = Bf + (size_t)(k0 + kb2) * N + n0;
            float2 r0 = *(const float2*)(bp + nb1);
            float2 r1 = *(const float2*)(bp + N + nb1);
            float2 r2 = *(const float2*)(bp + nb2);
            float2 r3 = *(const float2*)(bp + N + nb2);
            t0 = (unsigned)f2bf(r0.x) | ((unsigned)f2bf(r1.x) << 16);
            t1 = (unsigned)f2bf(r0.y) | ((unsigned)f2bf(r1.y) << 16);
            t2 = (unsigned)f2bf(r2.x) | ((unsigned)f2bf(r3.x) << 16);
            t3 = (unsigned)f2bf(r2.y) | ((unsigned)f2bf(r3.y) << 16);
        } else {
            const unsigned short* Bb = (const unsigned short*)Bv;
            const unsigned short* bp = Bb + (size_t)(k0 + kb2) * N + n0;
            unsigned int r0 = *(const unsigned int*)(bp + nb1);
            unsigned int r1 = *(const unsigned int*)(bp + N + nb1);
            unsigned int r2 = *(const unsigned int*)(bp + nb2);
            unsigned int r3 = *(const unsigned int*)(bp + N + nb2);
            t0 = (r0 & 0xffffu) | (r1 << 16);
            t1 = (r0 >> 16) | (r1 & 0xffff0000u);
            t2 = (r2 & 0xffffu) | (r3 << 16);
            t3 = (r2 >> 16) | (r3 & 0xffff0000u);
        }

        *(uint4*)(As + a_row * 32 + a_col) = av;
        *(unsigned int*)(BsT + nb1 * 32 + kb2)       = t0;
        *(unsigned int*)(BsT + (nb1 + 1) * 32 + kb2) = t1;
        *(unsigned int*)(BsT + nb2 * 32 + kb2)       = t2;
        *(unsigned int*)(BsT + (nb2 + 1) * 32 + kb2) = t3;
        __syncthreads();

        bf16x8 af = *(const bf16x8*)(As + (wave * 16 + mrow) * 32 + quad * 8);
        #pragma unroll
        for (int nt = 0; nt < 4; ++nt) {
            bf16x8 bfv = *(const bf16x8*)(BsT + (nt * 16 + mrow) * 32 + quad * 8);
            acc[nt] = __builtin_amdgcn_mfma_f32_16x16x32_bf16(af, bfv, acc[nt], 0, 0, 0);
        }
        __syncthreads();
    }
}

// ---------------------------------------------------------------------------
// QKV GEMM: Q is pre-scaled by 1/sqrt(D)=0.125 at write (folded softmax scale)
// ---------------------------------------------------------------------------
template<bool FP32>
__device__ __forceinline__ void qkv_body(
    const void* A, const void* Bw, const void* bias,
    unsigned short* Qb, unsigned short* Kb, unsigned short* Vb,
    unsigned short* As, unsigned short* BsT)
{
    const int K = 1024, N = 3072;
    const int m0 = blockIdx.y * 64;
    const int n0 = blockIdx.x * 64;

    f32x4 acc[4];
    #pragma unroll
    for (int nt = 0; nt < 4; ++nt) { acc[nt][0]=0.f; acc[nt][1]=0.f; acc[nt][2]=0.f; acc[nt][3]=0.f; }

    gemm_mainloop<FP32, FP32>(A, Bw, K, N, m0, n0, As, BsT, acc);

    const int tid  = threadIdx.x;
    const int wave = tid >> 6;
    const int lane = tid & 63;
    const int mrow = lane & 15;
    const int quad = lane >> 4;

    const int sel = n0 >> 10;
    const int h   = (n0 & 1023) >> 6;
    unsigned short* dst = (sel == 0) ? Qb : (sel == 1) ? Kb : Vb;
    const float scale = (sel == 0) ? 0.125f : 1.0f;

    #pragma unroll
    for (int nt = 0; nt < 4; ++nt) {
        const int d  = nt * 16 + mrow;
        const float bv = FP32 ? ((const float*)bias)[n0 + d]
                              : bf2f(((const unsigned short*)bias)[n0 + d]);
        #pragma unroll
        for (int r = 0; r < 4; ++r) {
            const int m  = m0 + wave * 16 + quad * 4 + r;
            const int bb = m >> 11;
            const int t  = m & 2047;
            dst[(((size_t)(bb * 16 + h) * 2048 + t) << 6) + d] = f2bf((acc[nt][r] + bv) * scale);
        }
    }
}

__global__ __launch_bounds__(256) void gemm_qkv_kernel(
    const int* __restrict__ flag,
    const void* __restrict__ A, const void* __restrict__ Bw,
    const void* __restrict__ bias,
    unsigned short* __restrict__ Qb, unsigned short* __restrict__ Kb,
    unsigned short* __restrict__ Vb)
{
    __shared__ unsigned short As[64 * 32];
    __shared__ unsigned short BsT[64 * 32];
    if (*flag) qkv_body<true >(A, Bw, bias, Qb, Kb, Vb, As, BsT);
    else       qkv_body<false>(A, Bw, bias, Qb, Kb, Vb, As, BsT);
}

// ---------------------------------------------------------------------------
// Proj GEMM
// ---------------------------------------------------------------------------
template<bool FP32>
__device__ __forceinline__ void proj_body(
    const unsigned short* A, const void* Bw, const void* bias, void* Out,
    unsigned short* As, unsigned short* BsT)
{
    const int K = 1024, N = 1024;
    const int m0 = blockIdx.y * 64;
    const int n0 = blockIdx.x * 64;

    f32x4 acc[4];
    #pragma unroll
    for (int nt = 0; nt < 4; ++nt) { acc[nt][0]=0.f; acc[nt][1]=0.f; acc[nt][2]=0.f; acc[nt][3]=0.f; }

    gemm_mainloop<false, FP32>(A, Bw, K, N, m0, n0, As, BsT, acc);

    const int tid  = threadIdx.x;
    const int wave = tid >> 6;
    const int lane = tid & 63;
    const int mrow = lane & 15;
    const int quad = lane >> 4;

    #pragma unroll
    for (int nt = 0; nt < 4; ++nt) {
        const int n  = n0 + nt * 16 + mrow;
        const float bv = FP32 ? ((const float*)bias)[n]
                              : bf2f(((const unsigned short*)bias)[n]);
        #pragma unroll
        for (int r = 0; r < 4; ++r) {
            const int m = m0 + wave * 16 + quad * 4 + r;
            const float val = acc[nt][r] + bv;
            if (FP32) ((float*)Out)[(size_t)m * 1024 + n] = val;
            else      ((unsigned short*)Out)[(size_t)m * 1024 + n] = f2bf(val);
        }
    }
}

__global__ __launch_bounds__(256) void gemm_proj_kernel(
    const int* __restrict__ flag,
    const unsigned short* __restrict__ A, const void* __restrict__ Bw,
    const void* __restrict__ bias, void* __restrict__ Out)
{
    __shared__ unsigned short As[64 * 32];
    __shared__ unsigned short BsT[64 * 32];
    if (*flag) proj_body<true >(A, Bw, bias, Out, As, BsT);
    else       proj_body<false>(A, Bw, bias, Out, As, BsT);
}

// ---------------------------------------------------------------------------
// MFMA flash attention. Block = 256 threads (4 waves) = one (b,h) x two
// 64-query tiles {i, 31-i} (uniform 33 K-tiles/block). 16x16x32 bf16 MFMA
// for QK^T and PV. LDS rows padded +8 shorts (2-way max bank aliasing, free).
// P round-trips through wave-private LDS rows (threadfence only, no barrier).
// Q arrives pre-scaled by 1/sqrt(D).
// ---------------------------------------------------------------------------
__global__ __launch_bounds__(256) void attn_kernel(
    const unsigned short* __restrict__ Qb,
    const unsigned short* __restrict__ Kb,
    const unsigned short* __restrict__ Vb,
    unsigned short* __restrict__ Attn)
{
    __shared__ unsigned short Qs[64][72];
    __shared__ unsigned short Ks[64][72];
    __shared__ unsigned short VsT[64][72];   // [d][j]
    __shared__ unsigned short Ps[64][72];

    const int tid  = threadIdx.x;
    const int wave = tid >> 6;
    const int lane = tid & 63;
    const int mrow = lane & 15;
    const int quad = lane >> 4;
    const int bh   = blockIdx.y;            // 0..31
    const int b    = bh >> 4, h = bh & 15;

    // staging indices
    const int jr  = tid >> 2;               // 0..63 (row copy)
    const int c16 = (tid & 3) << 4;         // 0,16,32,48
    const int j2  = (tid & 31) << 1;        // V-transpose: j pair
    const int dg  = (tid >> 5) << 3;        // V-transpose: d group of 8

    const unsigned short* Qbase = Qb + ((size_t)bh * 2048) * 64;
    const unsigned short* Kbase = Kb + ((size_t)bh * 2048) * 64;
    const unsigned short* Vbase = Vb + ((size_t)bh * 2048) * 64;

    for (int half = 0; half < 2; ++half) {
        const int qblk = (half == 0) ? (int)blockIdx.x : (31 - (int)blockIdx.x);
        const int q0   = qblk << 6;

        __syncthreads();   // all waves done with Qs before restage
        {
            const unsigned short* src = Qbase + (size_t)(q0 + jr) * 64 + c16;
            *(uint4*)&Qs[jr][c16]     = *(const uint4*)src;
            *(uint4*)&Qs[jr][c16 + 8] = *(const uint4*)(src + 8);
        }

        f32x4 Oa[4];
        #pragma unroll
        for (int dt = 0; dt < 4; ++dt) { Oa[dt][0]=0.f; Oa[dt][1]=0.f; Oa[dt][2]=0.f; Oa[dt][3]=0.f; }
        float m_run[4] = {-1e30f, -1e30f, -1e30f, -1e30f};
        float l_run[4] = {0.f, 0.f, 0.f, 0.f};

        const int ntiles = qblk + 1;
        for (int tile = 0; tile < ntiles; ++tile) {
            const int kt0 = tile << 6;
            __syncthreads();   // prior tile's Ks/VsT reads done
            {
                const unsigned short* ksrc = Kbase + (size_t)(kt0 + jr) * 64 + c16;
                *(uint4*)&Ks[jr][c16]     = *(const uint4*)ksrc;
                *(uint4*)&Ks[jr][c16 + 8] = *(const uint4*)(ksrc + 8);
                // V transposed: VsT[d][j]
                const unsigned short* v0p = Vbase + (size_t)(kt0 + j2) * 64 + dg;
                uint4 va = *(const uint4*)v0p;
                uint4 vb = *(const uint4*)(v0p + 64);
                unsigned int aw[4] = {va.x, va.y, va.z, va.w};
                unsigned int bw[4] = {vb.x, vb.y, vb.z, vb.w};
                #pragma unroll
                for (int c2 = 0; c2 < 4; ++c2) {
                    unsigned int lo = aw[c2], hi = bw[c2];
                    *(unsigned int*)&VsT[dg + 2 * c2][j2]     = (lo & 0xffffu) | (hi << 16);
                    *(unsigned int*)&VsT[dg + 2 * c2 + 1][j2] = (lo >> 16) | (hi & 0xffff0000u);
                }
            }
            __syncthreads();

            // ---- S = Q K^T (per wave: 16 q-rows x 64 keys) ----
            f32x4 sacc[4];
            #pragma unroll
            for (int jt = 0; jt < 4; ++jt) { sacc[jt][0]=0.f; sacc[jt][1]=0.f; sacc[jt][2]=0.f; sacc[jt][3]=0.f; }
            #pragma unroll
            for (int ks = 0; ks < 2; ++ks) {
                bf16x8 aq = *(const bf16x8*)&Qs[wave * 16 + mrow][ks * 32 + quad * 8];
                #pragma unroll
                for (int jt = 0; jt < 4; ++jt) {
                    bf16x8 bk = *(const bf16x8*)&Ks[jt * 16 + mrow][ks * 32 + quad * 8];
                    sacc[jt] = __builtin_amdgcn_mfma_f32_16x16x32_bf16(aq, bk, sacc[jt], 0, 0, 0);
                }
            }

            // ---- causal mask (only the diagonal tile) ----
            if (tile == ntiles - 1) {
                #pragma unroll
                for (int jt = 0; jt < 4; ++jt) {
                    const int j = jt * 16 + mrow;
                    #pragma unroll
                    for (int r = 0; r < 4; ++r) {
                        if (j > wave * 16 + quad * 4 + r) sacc[jt][r] = -1e30f;
                    }
                }
            }

            // ---- online softmax (row state per r; reduce over 16-lane quad group) ----
            float mx[4], alpha[4];
            #pragma unroll
            for (int r = 0; r < 4; ++r)
                mx[r] = fmaxf(fmaxf(sacc[0][r], sacc[1][r]), fmaxf(sacc[2][r], sacc[3][r]));
            #pragma unroll
            for (int m = 1; m <= 8; m <<= 1) {
                #pragma unroll
                for (int r = 0; r < 4; ++r) mx[r] = fmaxf(mx[r], __shfl_xor(mx[r], m));
            }
            #pragma unroll
            for (int r = 0; r < 4; ++r) {
                const float m_new = fmaxf(m_run[r], mx[r]);
                alpha[r] = __expf(m_run[r] - m_new);
                m_run[r] = m_new;
            }

            float ps[4] = {0.f, 0.f, 0.f, 0.f};
            #pragma unroll
            for (int jt = 0; jt < 4; ++jt) {
                #pragma unroll
                for (int r = 0; r < 4; ++r) {
                    const float pv = __expf(sacc[jt][r] - m_run[r]);
                    const unsigned short pb = f2bf(pv);
                    Ps[wave * 16 + quad * 4 + r][jt * 16 + mrow] = pb;
                    ps[r] += bf2f(pb);   // consistent with bf16 P used in PV
                }
            }
            #pragma unroll
            for (int m = 1; m <= 8; m <<= 1) {
                #pragma unroll
                for (int r = 0; r < 4; ++r) ps[r] += __shfl_xor(ps[r], m);
            }
            #pragma unroll
            for (int r = 0; r < 4; ++r) l_run[r] = l_run[r] * alpha[r] + ps[r];

            #pragma unroll
            for (int dt = 0; dt < 4; ++dt) {
                #pragma unroll
                for (int r = 0; r < 4; ++r) Oa[dt][r] *= alpha[r];
            }

            __threadfence_block();   // Ps writes -> Ps reads (wave-private rows)

            // ---- O += P V ----
            #pragma unroll
            for (int ks = 0; ks < 2; ++ks) {
                bf16x8 ap = *(const bf16x8*)&Ps[wave * 16 + mrow][ks * 32 + quad * 8];
                #pragma unroll
                for (int dt = 0; dt < 4; ++dt) {
                    bf16x8 bv = *(const bf16x8*)&VsT[dt * 16 + mrow][ks * 32 + quad * 8];
                    Oa[dt] = __builtin_amdgcn_mfma_f32_16x16x32_bf16(ap, bv, Oa[dt], 0, 0, 0);
                }
            }
        }

        // ---- epilogue ----
        #pragma unroll
        for (int r = 0; r < 4; ++r) {
            const float inv = 1.0f / l_run[r];
            const int t = q0 + wave * 16 + quad * 4 + r;
            const size_t base = ((size_t)(b * 2048 + t)) * 1024 + h * 64;
            #pragma unroll
            for (int dt = 0; dt < 4; ++dt)
                Attn[base + dt * 16 + mrow] = f2bf(Oa[dt][r] * inv);
        }
    }
}

// ---------------------------------------------------------------------------
extern "C" void kernel_launch(void* const* d_in, const int* in_sizes, int n_in,
                              void* d_out, int out_size, void* d_ws, size_t ws_size,
                              hipStream_t stream)
{
    const void* x     = d_in[0];
    const void* Wqkv  = d_in[1];
    const void* bqkv  = d_in[2];
    const void* Wproj = d_in[3];
    const void* bproj = d_in[4];

    int* flag = (int*)d_ws;
    unsigned short* ws   = (unsigned short*)d_ws;
    unsigned short* Qb   = ws + 64;
    unsigned short* Kb   = Qb + 4194304;
    unsigned short* Vb   = Kb + 4194304;
    unsigned short* Attn = Vb + 4194304;

    detect_dtype_kernel<<<1, 256, 0, stream>>>((const unsigned short*)x, flag);
    gemm_qkv_kernel<<<dim3(48, 64), 256, 0, stream>>>(flag, x, Wqkv, bqkv, Qb, Kb, Vb);
    // 16 query-tile pairs x 32 (b,h): uniform 33 K-tiles per block
    attn_kernel<<<dim3(16, 32), 256, 0, stream>>>(Qb, Kb, Vb, Attn);
    gemm_proj_kernel<<<dim3(16, 64), 256, 0, stream>>>(flag, Attn, Wproj, bproj, d_out);
}

// Round 5
// 235.670 us; speedup vs baseline: 4.3969x; 1.8285x over previous
//
#include <hip/hip_runtime.h>
#include <cstddef>

typedef __bf16 bf16x8 __attribute__((ext_vector_type(8)));
typedef float  f32x4  __attribute__((ext_vector_type(4)));

__device__ __forceinline__ float bf2f(unsigned short s) {
    return __uint_as_float(((unsigned int)s) << 16);
}
__device__ __forceinline__ unsigned short f2bf(float x) {
    unsigned int u = __float_as_uint(x);
    unsigned int r = u + 0x7fffu + ((u >> 16) & 1u);   // RNE
    return (unsigned short)(r >> 16);
}

// global -> LDS async copy, 16 B/lane. LDS dest is wave-uniform base + lane*16.
__device__ __forceinline__ void async_load16(const void* g, void* l) {
    __builtin_amdgcn_global_load_lds(
        (const __attribute__((address_space(1))) unsigned int*)g,
        (__attribute__((address_space(3))) unsigned int*)l,
        16, 0, 0);
}

// ---------------------------------------------------------------------------
// dtype detector (inputs confirmed fp32; cheap insurance, input-agnostic)
// ---------------------------------------------------------------------------
__global__ __launch_bounds__(256) void detect_dtype_kernel(
    const unsigned short* __restrict__ x, int* __restrict__ flag)
{
    __shared__ int cnt;
    if (threadIdx.x == 0) cnt = 0;
    __syncthreads();
    int wild = 0;
    for (int k = 0; k < 16; ++k) {
        unsigned short u = x[(size_t)((k * 256 + threadIdx.x) << 1)];
        int e = (u >> 7) & 0xFF;
        wild += ((e >= 0x90) || (e >= 1 && e <= 0x48)) ? 1 : 0;
    }
    atomicAdd(&cnt, wild);
    __syncthreads();
    if (threadIdx.x == 0) *flag = (cnt > 512) ? 1 : 0;
}

// ---------------------------------------------------------------------------
// cast fp32 -> bf16 (or copy bf16), 8 elements/thread
// ---------------------------------------------------------------------------
__global__ __launch_bounds__(256) void cast_kernel(
    const int* __restrict__ flag, const void* __restrict__ src,
    unsigned short* __restrict__ dst, int n8)
{
    const int i = blockIdx.x * 256 + threadIdx.x;
    if (i >= n8) return;
    const size_t off = (size_t)i * 8;
    if (*flag) {
        const float* s = (const float*)src + off;
        float4 a = *(const float4*)s;
        float4 b = *(const float4*)(s + 4);
        uint4 o;
        o.x = (unsigned)f2bf(a.x) | ((unsigned)f2bf(a.y) << 16);
        o.y = (unsigned)f2bf(a.z) | ((unsigned)f2bf(a.w) << 16);
        o.z = (unsigned)f2bf(b.x) | ((unsigned)f2bf(b.y) << 16);
        o.w = (unsigned)f2bf(b.z) | ((unsigned)f2bf(b.w) << 16);
        *(uint4*)(dst + off) = o;
    } else {
        *(uint4*)(dst + off) = *(const uint4*)((const unsigned short*)src + off);
    }
}

// ---------------------------------------------------------------------------
// transpose + cast: src [R][C] fp32/bf16 -> dst [C][R] bf16. 64x64 tiles.
// ---------------------------------------------------------------------------
__global__ __launch_bounds__(256) void transpose_cast_kernel(
    const int* __restrict__ flag, const void* __restrict__ src,
    unsigned short* __restrict__ dst, int R, int C)
{
    __shared__ unsigned short T[64][72];
    const int c0 = blockIdx.x * 64, r0 = blockIdx.y * 64;
    const int t  = threadIdx.x;
    const int r  = t >> 2, cl = (t & 3) << 4;

    unsigned short v[16];
    if (*flag) {
        const float* s = (const float*)src + (size_t)(r0 + r) * C + c0 + cl;
        #pragma unroll
        for (int q = 0; q < 4; ++q) {
            float4 a = *(const float4*)(s + q * 4);
            v[q * 4 + 0] = f2bf(a.x); v[q * 4 + 1] = f2bf(a.y);
            v[q * 4 + 2] = f2bf(a.z); v[q * 4 + 3] = f2bf(a.w);
        }
    } else {
        const unsigned short* s = (const unsigned short*)src + (size_t)(r0 + r) * C + c0 + cl;
        uint4 a = *(const uint4*)s;
        uint4 b = *(const uint4*)(s + 8);
        unsigned int w[8] = {a.x, a.y, a.z, a.w, b.x, b.y, b.z, b.w};
        #pragma unroll
        for (int q = 0; q < 8; ++q) {
            v[q * 2]     = (unsigned short)(w[q] & 0xffffu);
            v[q * 2 + 1] = (unsigned short)(w[q] >> 16);
        }
    }
    #pragma unroll
    for (int c = 0; c < 16; ++c) T[cl + c][r] = v[c];
    __syncthreads();

    const int c = t >> 2, rl = (t & 3) << 4;
    uint4 o0 = *(const uint4*)&T[c][rl];
    uint4 o1 = *(const uint4*)&T[c][rl + 8];
    unsigned short* dp = dst + (size_t)(c0 + c) * R + r0 + rl;
    *(uint4*)dp       = o0;
    *(uint4*)(dp + 8) = o1;
}

// ---------------------------------------------------------------------------
// m97-style BT GEMM mainloop: C(128x128) += A[m0+128,:K] * BT[n0+128,:K]^T
// A, BT bf16 row-major [.,K]. BK=32, 4 waves in 2x2 quadrants, 4x4 MFMA acc.
// Staging via global_load_lds 16B into unpadded [128][32] LDS tiles.
// ---------------------------------------------------------------------------
__device__ __forceinline__ void bt_mainloop(
    const unsigned short* __restrict__ A,
    const unsigned short* __restrict__ BT,
    int K, int m0, int n0,
    unsigned short* As, unsigned short* Bs,
    f32x4 (&acc)[4][4])
{
    const int tid  = threadIdx.x;
    const int wave = tid >> 6;
    const int lane = tid & 63;
    const int mrow = lane & 15;
    const int quad = lane >> 4;
    const int wr = wave >> 1, wc = wave & 1;
    const int srow = tid >> 2;
    const int scol = (tid & 3) << 3;

    const unsigned short* ga  = A  + (size_t)(m0 + srow) * K + scol;
    const unsigned short* ga2 = ga + (size_t)64 * K;
    const unsigned short* gb  = BT + (size_t)(n0 + srow) * K + scol;
    const unsigned short* gb2 = gb + (size_t)64 * K;
    unsigned short* lA  = As + wave * 512;          // wave-uniform bases
    unsigned short* lA2 = As + 2048 + wave * 512;
    unsigned short* lB  = Bs + wave * 512;
    unsigned short* lB2 = Bs + 2048 + wave * 512;

    for (int k0 = 0; k0 < K; k0 += 32) {
        async_load16(ga,  lA);
        async_load16(ga2, lA2);
        async_load16(gb,  lB);
        async_load16(gb2, lB2);
        ga += 32; ga2 += 32; gb += 32; gb2 += 32;
        __syncthreads();    // drains vmcnt -> staging complete

        bf16x8 afr[4], bfr[4];
        #pragma unroll
        for (int mt = 0; mt < 4; ++mt)
            afr[mt] = *(const bf16x8*)(As + (wr * 64 + mt * 16 + mrow) * 32 + quad * 8);
        #pragma unroll
        for (int nt = 0; nt < 4; ++nt)
            bfr[nt] = *(const bf16x8*)(Bs + (wc * 64 + nt * 16 + mrow) * 32 + quad * 8);
        #pragma unroll
        for (int mt = 0; mt < 4; ++mt) {
            #pragma unroll
            for (int nt = 0; nt < 4; ++nt)
                acc[mt][nt] = __builtin_amdgcn_mfma_f32_16x16x32_bf16(
                    afr[mt], bfr[nt], acc[mt][nt], 0, 0, 0);
        }
        __syncthreads();    // LDS reads done before restage
    }
}

// ---------------------------------------------------------------------------
// QKV GEMM (BT form): xb[4096,1024] @ WqkvT[3072,1024]^T + bqkv
// Q pre-scaled by 1/sqrt(D)=0.125, scattered to Q/K/V [B,H,T,D] bf16
// ---------------------------------------------------------------------------
__global__ __launch_bounds__(256) void gemm_qkv_bt(
    const int* __restrict__ flag,
    const unsigned short* __restrict__ A,
    const unsigned short* __restrict__ BT,
    const void* __restrict__ bias,
    unsigned short* __restrict__ Qb, unsigned short* __restrict__ Kb,
    unsigned short* __restrict__ Vb)
{
    __shared__ unsigned short As[128 * 32];
    __shared__ unsigned short Bs[128 * 32];
    const int m0 = blockIdx.y * 128, n0 = blockIdx.x * 128;

    f32x4 acc[4][4];
    #pragma unroll
    for (int mt = 0; mt < 4; ++mt)
        #pragma unroll
        for (int nt = 0; nt < 4; ++nt)
            { acc[mt][nt][0]=0.f; acc[mt][nt][1]=0.f; acc[mt][nt][2]=0.f; acc[mt][nt][3]=0.f; }

    bt_mainloop(A, BT, 1024, m0, n0, As, Bs, acc);

    const int tid  = threadIdx.x;
    const int wave = tid >> 6;
    const int lane = tid & 63;
    const int mrow = lane & 15;
    const int quad = lane >> 4;
    const int wr = wave >> 1, wc = wave & 1;
    const bool f32b = (*flag != 0);

    #pragma unroll
    for (int nt = 0; nt < 4; ++nt) {
        const int n = n0 + wc * 64 + nt * 16 + mrow;
        const float bv = f32b ? ((const float*)bias)[n]
                              : bf2f(((const unsigned short*)bias)[n]);
        const int sel = n >> 10;
        const int h   = (n & 1023) >> 6;
        const int d   = n & 63;
        unsigned short* dst = (sel == 0) ? Qb : (sel == 1) ? Kb : Vb;
        const float sc = (sel == 0) ? 0.125f : 1.0f;
        #pragma unroll
        for (int mt = 0; mt < 4; ++mt) {
            #pragma unroll
            for (int r = 0; r < 4; ++r) {
                const int m  = m0 + wr * 64 + mt * 16 + quad * 4 + r;
                const int bb = m >> 11;
                const int t  = m & 2047;
                dst[(((size_t)(bb * 16 + h) * 2048 + t) << 6) + d] =
                    f2bf((acc[mt][nt][r] + bv) * sc);
            }
        }
    }
}

// ---------------------------------------------------------------------------
// Proj GEMM (BT form): Attn[4096,1024] @ WprojT[1024,1024]^T + bproj -> out
// ---------------------------------------------------------------------------
__global__ __launch_bounds__(256) void gemm_proj_bt(
    const int* __restrict__ flag,
    const unsigned short* __restrict__ A,
    const unsigned short* __restrict__ BT,
    const void* __restrict__ bias, void* __restrict__ Out)
{
    __shared__ unsigned short As[128 * 32];
    __shared__ unsigned short Bs[128 * 32];
    const int m0 = blockIdx.y * 128, n0 = blockIdx.x * 128;

    f32x4 acc[4][4];
    #pragma unroll
    for (int mt = 0; mt < 4; ++mt)
        #pragma unroll
        for (int nt = 0; nt < 4; ++nt)
            { acc[mt][nt][0]=0.f; acc[mt][nt][1]=0.f; acc[mt][nt][2]=0.f; acc[mt][nt][3]=0.f; }

    bt_mainloop(A, BT, 1024, m0, n0, As, Bs, acc);

    const int tid  = threadIdx.x;
    const int wave = tid >> 6;
    const int lane = tid & 63;
    const int mrow = lane & 15;
    const int quad = lane >> 4;
    const int wr = wave >> 1, wc = wave & 1;
    const bool f32b = (*flag != 0);

    #pragma unroll
    for (int nt = 0; nt < 4; ++nt) {
        const int n = n0 + wc * 64 + nt * 16 + mrow;
        const float bv = f32b ? ((const float*)bias)[n]
                              : bf2f(((const unsigned short*)bias)[n]);
        #pragma unroll
        for (int mt = 0; mt < 4; ++mt) {
            #pragma unroll
            for (int r = 0; r < 4; ++r) {
                const int m = m0 + wr * 64 + mt * 16 + quad * 4 + r;
                const float val = acc[mt][nt][r] + bv;
                if (f32b) ((float*)Out)[(size_t)m * 1024 + n] = val;
                else      ((unsigned short*)Out)[(size_t)m * 1024 + n] = f2bf(val);
            }
        }
    }
}

// ---------------------------------------------------------------------------
// MFMA flash attention (unchanged from R4, known-correct)
// ---------------------------------------------------------------------------
__global__ __launch_bounds__(256) void attn_kernel(
    const unsigned short* __restrict__ Qb,
    const unsigned short* __restrict__ Kb,
    const unsigned short* __restrict__ Vb,
    unsigned short* __restrict__ Attn)
{
    __shared__ unsigned short Qs[64][72];
    __shared__ unsigned short Ks[64][72];
    __shared__ unsigned short VsT[64][72];
    __shared__ unsigned short Ps[64][72];

    const int tid  = threadIdx.x;
    const int wave = tid >> 6;
    const int lane = tid & 63;
    const int mrow = lane & 15;
    const int quad = lane >> 4;
    const int bh   = blockIdx.y;
    const int b    = bh >> 4, h = bh & 15;

    const int jr  = tid >> 2;
    const int c16 = (tid & 3) << 4;
    const int j2  = (tid & 31) << 1;
    const int dg  = (tid >> 5) << 3;

    const unsigned short* Qbase = Qb + ((size_t)bh * 2048) * 64;
    const unsigned short* Kbase = Kb + ((size_t)bh * 2048) * 64;
    const unsigned short* Vbase = Vb + ((size_t)bh * 2048) * 64;

    for (int half = 0; half < 2; ++half) {
        const int qblk = (half == 0) ? (int)blockIdx.x : (31 - (int)blockIdx.x);
        const int q0   = qblk << 6;

        __syncthreads();
        {
            const unsigned short* src = Qbase + (size_t)(q0 + jr) * 64 + c16;
            *(uint4*)&Qs[jr][c16]     = *(const uint4*)src;
            *(uint4*)&Qs[jr][c16 + 8] = *(const uint4*)(src + 8);
        }

        f32x4 Oa[4];
        #pragma unroll
        for (int dt = 0; dt < 4; ++dt) { Oa[dt][0]=0.f; Oa[dt][1]=0.f; Oa[dt][2]=0.f; Oa[dt][3]=0.f; }
        float m_run[4] = {-1e30f, -1e30f, -1e30f, -1e30f};
        float l_run[4] = {0.f, 0.f, 0.f, 0.f};

        const int ntiles = qblk + 1;
        for (int tile = 0; tile < ntiles; ++tile) {
            const int kt0 = tile << 6;
            __syncthreads();
            {
                const unsigned short* ksrc = Kbase + (size_t)(kt0 + jr) * 64 + c16;
                *(uint4*)&Ks[jr][c16]     = *(const uint4*)ksrc;
                *(uint4*)&Ks[jr][c16 + 8] = *(const uint4*)(ksrc + 8);
                const unsigned short* v0p = Vbase + (size_t)(kt0 + j2) * 64 + dg;
                uint4 va = *(const uint4*)v0p;
                uint4 vb = *(const uint4*)(v0p + 64);
                unsigned int aw[4] = {va.x, va.y, va.z, va.w};
                unsigned int bw[4] = {vb.x, vb.y, vb.z, vb.w};
                #pragma unroll
                for (int c2 = 0; c2 < 4; ++c2) {
                    unsigned int lo = aw[c2], hi = bw[c2];
                    *(unsigned int*)&VsT[dg + 2 * c2][j2]     = (lo & 0xffffu) | (hi << 16);
                    *(unsigned int*)&VsT[dg + 2 * c2 + 1][j2] = (lo >> 16) | (hi & 0xffff0000u);
                }
            }
            __syncthreads();

            f32x4 sacc[4];
            #pragma unroll
            for (int jt = 0; jt < 4; ++jt) { sacc[jt][0]=0.f; sacc[jt][1]=0.f; sacc[jt][2]=0.f; sacc[jt][3]=0.f; }
            #pragma unroll
            for (int ks = 0; ks < 2; ++ks) {
                bf16x8 aq = *(const bf16x8*)&Qs[wave * 16 + mrow][ks * 32 + quad * 8];
                #pragma unroll
                for (int jt = 0; jt < 4; ++jt) {
                    bf16x8 bk = *(const bf16x8*)&Ks[jt * 16 + mrow][ks * 32 + quad * 8];
                    sacc[jt] = __builtin_amdgcn_mfma_f32_16x16x32_bf16(aq, bk, sacc[jt], 0, 0, 0);
                }
            }

            if (tile == ntiles - 1) {
                #pragma unroll
                for (int jt = 0; jt < 4; ++jt) {
                    const int j = jt * 16 + mrow;
                    #pragma unroll
                    for (int r = 0; r < 4; ++r) {
                        if (j > wave * 16 + quad * 4 + r) sacc[jt][r] = -1e30f;
                    }
                }
            }

            float mx[4], alpha[4];
            #pragma unroll
            for (int r = 0; r < 4; ++r)
                mx[r] = fmaxf(fmaxf(sacc[0][r], sacc[1][r]), fmaxf(sacc[2][r], sacc[3][r]));
            #pragma unroll
            for (int m = 1; m <= 8; m <<= 1) {
                #pragma unroll
                for (int r = 0; r < 4; ++r) mx[r] = fmaxf(mx[r], __shfl_xor(mx[r], m));
            }
            #pragma unroll
            for (int r = 0; r < 4; ++r) {
                const float m_new = fmaxf(m_run[r], mx[r]);
                alpha[r] = __expf(m_run[r] - m_new);
                m_run[r] = m_new;
            }

            float ps[4] = {0.f, 0.f, 0.f, 0.f};
            #pragma unroll
            for (int jt = 0; jt < 4; ++jt) {
                #pragma unroll
                for (int r = 0; r < 4; ++r) {
                    const float pv = __expf(sacc[jt][r] - m_run[r]);
                    const unsigned short pb = f2bf(pv);
                    Ps[wave * 16 + quad * 4 + r][jt * 16 + mrow] = pb;
                    ps[r] += bf2f(pb);
                }
            }
            #pragma unroll
            for (int m = 1; m <= 8; m <<= 1) {
                #pragma unroll
                for (int r = 0; r < 4; ++r) ps[r] += __shfl_xor(ps[r], m);
            }
            #pragma unroll
            for (int r = 0; r < 4; ++r) l_run[r] = l_run[r] * alpha[r] + ps[r];

            #pragma unroll
            for (int dt = 0; dt < 4; ++dt) {
                #pragma unroll
                for (int r = 0; r < 4; ++r) Oa[dt][r] *= alpha[r];
            }

            __threadfence_block();

            #pragma unroll
            for (int ks = 0; ks < 2; ++ks) {
                bf16x8 ap = *(const bf16x8*)&Ps[wave * 16 + mrow][ks * 32 + quad * 8];
                #pragma unroll
                for (int dt = 0; dt < 4; ++dt) {
                    bf16x8 bv = *(const bf16x8*)&VsT[dt * 16 + mrow][ks * 32 + quad * 8];
                    Oa[dt] = __builtin_amdgcn_mfma_f32_16x16x32_bf16(ap, bv, Oa[dt], 0, 0, 0);
                }
            }
        }

        #pragma unroll
        for (int r = 0; r < 4; ++r) {
            const float inv = 1.0f / l_run[r];
            const int t = q0 + wave * 16 + quad * 4 + r;
            const size_t base = ((size_t)(b * 2048 + t)) * 1024 + h * 64;
            #pragma unroll
            for (int dt = 0; dt < 4; ++dt)
                Attn[base + dt * 16 + mrow] = f2bf(Oa[dt][r] * inv);
        }
    }
}

// ---------------------------------------------------------------------------
extern "C" void kernel_launch(void* const* d_in, const int* in_sizes, int n_in,
                              void* d_out, int out_size, void* d_ws, size_t ws_size,
                              hipStream_t stream)
{
    const void* x     = d_in[0];
    const void* Wqkv  = d_in[1];
    const void* bqkv  = d_in[2];
    const void* Wproj = d_in[3];
    const void* bproj = d_in[4];

    int* flag = (int*)d_ws;
    unsigned short* ws = (unsigned short*)d_ws;
    // layout (shorts): flag pad 64 | xb 4.19M | shared(WqkvT 3.15M / Attn 4.19M)
    //                  | WprojT 1.05M | Qb | Kb | Vb  (~44 MB total)
    unsigned short* xb     = ws + 64;
    unsigned short* shared = xb + 4194304;        // WqkvT first, Attn later
    unsigned short* WqkvT  = shared;
    unsigned short* Attn   = shared;
    unsigned short* WprojT = shared + 4194304;
    unsigned short* Qb     = WprojT + 1048576;
    unsigned short* Kb     = Qb + 4194304;
    unsigned short* Vb     = Kb + 4194304;

    detect_dtype_kernel<<<1, 256, 0, stream>>>((const unsigned short*)x, flag);
    // x [4096,1024] -> bf16 (row-major): 4194304/8 = 524288 threads
    cast_kernel<<<2048, 256, 0, stream>>>(flag, x, xb, 524288);
    // Wqkv [1024,3072] -> WqkvT [3072,1024] bf16
    transpose_cast_kernel<<<dim3(48, 16), 256, 0, stream>>>(flag, Wqkv, WqkvT, 1024, 3072);
    // Wproj [1024,1024] -> WprojT [1024,1024] bf16
    transpose_cast_kernel<<<dim3(16, 16), 256, 0, stream>>>(flag, Wproj, WprojT, 1024, 1024);
    // QKV: grid (3072/128, 4096/128) = (24, 32)
    gemm_qkv_bt<<<dim3(24, 32), 256, 0, stream>>>(flag, xb, WqkvT, bqkv, Qb, Kb, Vb);
    // attention: 16 query-tile pairs x 32 (b,h)
    attn_kernel<<<dim3(16, 32), 256, 0, stream>>>(Qb, Kb, Vb, Attn);
    // proj: grid (1024/128, 4096/128) = (8, 32)
    gemm_proj_bt<<<dim3(8, 32), 256, 0, stream>>>(flag, Attn, WprojT, bproj, d_out);
}